// Round 19
// baseline (235.704 us; speedup 1.0000x reference)
//
#include <hip/hip_runtime.h>
#include <hip/hip_bf16.h>
#include <climits>
#include <cstdint>
#include <cfloat>

#define NROWS   524288
#define KDIM    128
#define NGRAPH  64
#define NSTROKE 8192
#define EPSF    1e-5f

typedef __bf16 bf16x8 __attribute__((ext_vector_type(8)));
typedef float  f32x4  __attribute__((ext_vector_type(4)));

// ws layout (bytes)
#define WT_OFF    0                         // ushort bf16 Wt[256][128] (col-major)
#define CSUM_OFF  65536                     // float[256]
#define CSQ_OFF   66560                     // float[256]
#define ST_OFF    67584                     // int [8192][128] stroke max (int-key)
#define GT_OFF    (ST_OFF + NSTROKE*KDIM*4) // int [64][128] graph max (int-key)

__device__ __forceinline__ unsigned short f2bf(float f) {
  unsigned int u = __float_as_uint(f);
  u += 0x7fffu + ((u >> 16) & 1u);   // RNE
  return (unsigned short)(u >> 16);
}
// order-preserving float<->int key (for atomicMax)
__device__ __forceinline__ int fkey(float f) {
  int b = __float_as_int(f);
  return b >= 0 ? b : (b ^ 0x7fffffff);
}
__device__ __forceinline__ float fdec(int k) {
  int b = k >= 0 ? k : (k ^ 0x7fffffff);
  return __int_as_float(b);
}

// ---------------- init: weights -> bf16 col-major; clear sums + max tables ----
__global__ void k_init(const float* __restrict__ Wmax, const float* __restrict__ Wsk,
                       unsigned char* __restrict__ ws) {
  unsigned short* wt = (unsigned short*)(ws + WT_OFF);
  float* csum = (float*)(ws + CSUM_OFF);
  float* csq  = (float*)(ws + CSQ_OFF);
  int* st = (int*)(ws + ST_OFF);
  int* gt = (int*)(ws + GT_OFF);
  int i = blockIdx.x * blockDim.x + threadIdx.x;
  const int total = NSTROKE * KDIM;   // 1048576
  for (; i < total; i += gridDim.x * blockDim.x) {
    st[i] = INT_MIN;
    if (i < NGRAPH * KDIM) gt[i] = INT_MIN;
    if (i < 256) { csum[i] = 0.f; csq[i] = 0.f; }
    if (i < 256 * KDIM) {
      int c = i / KDIM, k = i % KDIM;
      float w = (c < 128) ? Wsk[k * 128 + c] : Wmax[k * 128 + (c - 128)];
      wt[i] = f2bf(w);   // wt[c][k]
    }
  }
}

// ---------------- pass1: 8-wave SLIM pipelined GEMM + sums + seg max -----------
// R19 = R18 (proven 226.9us) + tree-structured epilogue reductions: the
// 16-deep serial s/q/t dependency chains per column become depth-4 pairwise
// trees (squares as independent muls + add tree; max pairs fusable to
// v_max3_f32). All other code byte-identical to R18.
__global__ __launch_bounds__(512, 4) void k_pass1(const float* __restrict__ x,
                                                  const int* __restrict__ batch,
                                                  const int* __restrict__ stroke,
                                                  unsigned char* __restrict__ ws) {
  __shared__ __align__(16) unsigned short xs[2][64 * 128];  // 2 x 16 KB, swz
  const unsigned short* wt = (const unsigned short*)(ws + WT_OFF);
  float* csum = (float*)(ws + CSUM_OFF);
  float* csq  = (float*)(ws + CSQ_OFF);
  int* st = (int*)(ws + ST_OFF);
  int* gt = (int*)(ws + GT_OFF);

  const int tid  = threadIdx.x;
  const int lane = tid & 63;
  const int wv   = tid >> 6;   // wave 0..7
  const int lr   = lane & 15;
  const int lg   = lane >> 4;
  const int srow = tid >> 3;   // staging row (0..63)
  const int skg  = tid & 7;    // staging 16-float group

  const int colbase = wv * 32;            // combined col base
  const bool isS = (wv < 4);
  const int* __restrict__ segp = isS ? stroke : batch;
  int* __restrict__ tab = isS ? st : gt;
  const int tcol = colbase - (isS ? 0 : 128);

  // B fragments: lane holds Wt[col = colbase+n*16+lr][k = ks*32+lg*8 ..+7]
  bf16x8 bfrag[4][2];
#pragma unroll
  for (int ks = 0; ks < 4; ++ks)
#pragma unroll
    for (int n = 0; n < 2; ++n)
      bfrag[ks][n] = *(const bf16x8*)(wt + (colbase + n * 16 + lr) * KDIM + ks * 32 + lg * 8);

  float sumn[2] = {0.f, 0.f};
  float sqn[2]  = {0.f, 0.f};

  int   curseg = -1;
  float runmax[2] = {-FLT_MAX, -FLT_MAX};

#define FLUSH()                                                               \
  if (curseg >= 0) {                                                          \
    _Pragma("unroll")                                                         \
    for (int n = 0; n < 2; ++n) {                                             \
      float f = runmax[n];                                                    \
      f = fmaxf(f, __shfl_xor(f, 16));                                        \
      f = fmaxf(f, __shfl_xor(f, 32));                                        \
      if (lg == 0) atomicMax(&tab[curseg * KDIM + tcol + n * 16 + lr], fkey(f)); \
    }                                                                         \
  }

#define PF_LOAD(ROW0)                                                         \
  {                                                                           \
    const float* src = x + (size_t)((ROW0) + srow) * KDIM + skg * 16;         \
    pf[0] = *(const f32x4*)src;                                               \
    pf[1] = *(const f32x4*)(src + 4);                                         \
    pf[2] = *(const f32x4*)(src + 8);                                         \
    pf[3] = *(const f32x4*)(src + 12);                                        \
  }

#define PF_STORE(P)                                                           \
  {                                                                           \
    union { bf16x8 v; unsigned short u[8]; } pk;                              \
    pk.u[0] = f2bf(pf[0][0]); pk.u[1] = f2bf(pf[0][1]);                       \
    pk.u[2] = f2bf(pf[0][2]); pk.u[3] = f2bf(pf[0][3]);                       \
    pk.u[4] = f2bf(pf[1][0]); pk.u[5] = f2bf(pf[1][1]);                       \
    pk.u[6] = f2bf(pf[1][2]); pk.u[7] = f2bf(pf[1][3]);                       \
    *(bf16x8*)(xs[P] + srow * KDIM + (((skg * 2) ^ (srow & 7)) << 3)) = pk.v; \
    pk.u[0] = f2bf(pf[2][0]); pk.u[1] = f2bf(pf[2][1]);                       \
    pk.u[2] = f2bf(pf[2][2]); pk.u[3] = f2bf(pf[2][3]);                       \
    pk.u[4] = f2bf(pf[3][0]); pk.u[5] = f2bf(pf[3][1]);                       \
    pk.u[6] = f2bf(pf[3][2]); pk.u[7] = f2bf(pf[3][3]);                       \
    *(bf16x8*)(xs[P] + srow * KDIM + (((skg * 2 + 1) ^ (srow & 7)) << 3)) = pk.v; \
  }

// load seg ids for tile and derive (mask, seg0) immediately — off the
// epilogue critical path
#define SEG_PREP(ROW0, SV, MK, S0)                                            \
  {                                                                           \
    SV = segp[(ROW0) + lane];                                                 \
    int pv_ = __shfl_up(SV, 1);                                               \
    MK = __ballot(lane > 0 && pv_ != SV);                                     \
    S0 = __shfl(SV, 0);                                                       \
  }

  const int brow = blockIdx.x * 1024;   // 16 tiles x 64 rows
  f32x4 pf[4];
  int segv, seg0;
  unsigned long long mask;
  int segvN, seg0N;
  unsigned long long maskN;

  // ---- prologue: stage tile 0 ----
  PF_LOAD(brow);
  SEG_PREP(brow, segv, mask, seg0);
  PF_STORE(0);
  __syncthreads();

  int cur = 0;
  for (int ti = 0; ti < 16; ++ti) {
    // ---- issue next tile's global loads + seg prep (hidden under compute) ----
    if (ti < 15) {
      PF_LOAD(brow + (ti + 1) * 64);
      SEG_PREP(brow + (ti + 1) * 64, segvN, maskN, seg0N);
    }

    // ---- MFMA: 64 rows x 32 cols per wave, from xs[cur] ----
    f32x4 acc[4][2];
#pragma unroll
    for (int m = 0; m < 4; ++m)
#pragma unroll
      for (int n = 0; n < 2; ++n) { f32x4 z = {0.f, 0.f, 0.f, 0.f}; acc[m][n] = z; }

#pragma unroll
    for (int ks = 0; ks < 4; ++ks) {
      bf16x8 af[4];
#pragma unroll
      for (int m = 0; m < 4; ++m) {
        int r  = m * 16 + lr;
        int kg = ks * 4 + lg;
        af[m] = *(const bf16x8*)(xs[cur] + r * KDIM + ((kg ^ (r & 7)) << 3));
      }
#pragma unroll
      for (int m = 0; m < 4; ++m) {
        acc[m][0] = __builtin_amdgcn_mfma_f32_16x16x32_bf16(af[m], bfrag[ks][0], acc[m][0], 0, 0, 0);
        acc[m][1] = __builtin_amdgcn_mfma_f32_16x16x32_bf16(af[m], bfrag[ks][1], acc[m][1], 0, 0, 0);
      }
    }

    // ---- column sums/sumsq + tile col-max: pairwise trees (depth 4) ----
    float tm[2];
#pragma unroll
    for (int n = 0; n < 2; ++n) {
      float v0  = acc[0][n][0], v1  = acc[0][n][1], v2  = acc[0][n][2], v3  = acc[0][n][3];
      float v4  = acc[1][n][0], v5  = acc[1][n][1], v6  = acc[1][n][2], v7  = acc[1][n][3];
      float v8  = acc[2][n][0], v9  = acc[2][n][1], v10 = acc[2][n][2], v11 = acc[2][n][3];
      float v12 = acc[3][n][0], v13 = acc[3][n][1], v14 = acc[3][n][2], v15 = acc[3][n][3];
      // sum tree
      float sa = (v0 + v1) + (v2 + v3);
      float sb = (v4 + v5) + (v6 + v7);
      float sc_ = (v8 + v9) + (v10 + v11);
      float sd = (v12 + v13) + (v14 + v15);
      sumn[n] += (sa + sb) + (sc_ + sd);
      // sumsq: independent muls + add tree
      float qa = fmaf(v0, v0, v1 * v1) + fmaf(v2, v2, v3 * v3);
      float qb = fmaf(v4, v4, v5 * v5) + fmaf(v6, v6, v7 * v7);
      float qc = fmaf(v8, v8, v9 * v9) + fmaf(v10, v10, v11 * v11);
      float qd = fmaf(v12, v12, v13 * v13) + fmaf(v14, v14, v15 * v15);
      sqn[n] += (qa + qb) + (qc + qd);
      // max tree (fmaxf pairs -> clang can fuse v_max3)
      float ta = fmaxf(fmaxf(v0, v1), fmaxf(v2, v3));
      float tb = fmaxf(fmaxf(v4, v5), fmaxf(v6, v7));
      float tc = fmaxf(fmaxf(v8, v9), fmaxf(v10, v11));
      float td = fmaxf(fmaxf(v12, v13), fmaxf(v14, v15));
      tm[n] = fmaxf(fmaxf(ta, tb), fmaxf(tc, td));
    }

    // ---- acc-direct segment max; (mask, seg0) precomputed last iteration ----
    {
      if (mask == 0ull) {
        if (seg0 == curseg) {
#pragma unroll
          for (int n = 0; n < 2; ++n) runmax[n] = fmaxf(runmax[n], tm[n]);
        } else {
          FLUSH();
          curseg = seg0;
#pragma unroll
          for (int n = 0; n < 2; ++n) runmax[n] = tm[n];
        }
      } else {
        unsigned long long rem = mask;
        int a = 0;
        while (true) {
          int b = rem ? (int)__builtin_ctzll(rem) : 64;
          int segr = (a == 0) ? seg0 : __shfl(segv, a);
          float rm[2] = {-FLT_MAX, -FLT_MAX};
#pragma unroll
          for (int m = 0; m < 4; ++m)
#pragma unroll
            for (int rg = 0; rg < 4; ++rg) {
              int pos = m * 16 + lg * 4 + rg;
              bool in = (pos >= a) && (pos < b);
#pragma unroll
              for (int n = 0; n < 2; ++n)
                rm[n] = in ? fmaxf(rm[n], acc[m][n][rg]) : rm[n];
            }
          if (a == 0 && segr == curseg) {
#pragma unroll
            for (int n = 0; n < 2; ++n) runmax[n] = fmaxf(runmax[n], rm[n]);
          } else {
            FLUSH();
            curseg = segr;
#pragma unroll
            for (int n = 0; n < 2; ++n) runmax[n] = rm[n];
          }
          if (b >= 64) break;
          rem &= rem - 1; a = b;
        }
      }
    }

    // ---- write next tile into the other LDS buffer; one barrier per tile ----
    if (ti < 15) {
      PF_STORE(cur ^ 1);
      segv = segvN; mask = maskN; seg0 = seg0N;
    }
    __syncthreads();
    cur ^= 1;
  }

  FLUSH();   // final carried run

  // ---- finalize sums: reduce over the 4 k-group lanes, atomics at lg==0 ----
#pragma unroll
  for (int n = 0; n < 2; ++n) {
    float s = sumn[n], q = sqn[n];
    s += __shfl_xor(s, 16); s += __shfl_xor(s, 32);
    q += __shfl_xor(q, 16); q += __shfl_xor(q, 32);
    if (lg == 0) {
      atomicAdd(&csum[colbase + n * 16 + lr], s);
      atomicAdd(&csq [colbase + n * 16 + lr], q);
    }
  }
#undef FLUSH
#undef PF_LOAD
#undef PF_STORE
#undef SEG_PREP
}

// ---------------- out: gather + BN(affine)+ReLU on the fly + stream write ------
// (R2-exact)
__global__ __launch_bounds__(256) void k_out(const int* __restrict__ batch,
                                             const int* __restrict__ stroke,
                                             const float* __restrict__ g_max,
                                             const float* __restrict__ be_max,
                                             const float* __restrict__ g_sk,
                                             const float* __restrict__ be_sk,
                                             const unsigned char* __restrict__ ws,
                                             float* __restrict__ out) {
  const float* csum = (const float*)(ws + CSUM_OFF);
  const float* csq  = (const float*)(ws + CSQ_OFF);
  const int* st = (const int*)(ws + ST_OFF);
  const int* gt = (const int*)(ws + GT_OFF);

  const int lane = threadIdx.x & 63;
  const int wvid = blockIdx.x * 4 + (threadIdx.x >> 6);
  const int row0 = wvid * 64;
  const bool isS = lane < 32;
  const int  cg  = (isS ? lane : lane - 32) * 4;
  const int* tab  = isS ? st : gt;
  const int* idxp = isS ? stroke : batch;
  const float* gv = isS ? g_sk : g_max;
  const float* bv = isS ? be_sk : be_max;

  const float invN = 1.0f / (float)NROWS;
  f32x4 mu, sc, bb;
#pragma unroll
  for (int j = 0; j < 4; ++j) {
    int cc = (isS ? 0 : 128) + cg + j;
    float m  = csum[cc] * invN;
    float vr = csq[cc] * invN - m * m;
    mu[j] = m;
    sc[j] = gv[cg + j] * rsqrtf(vr + EPSF);
    bb[j] = bv[cg + j];
  }

  f32x4* out4 = (f32x4*)out;
#pragma unroll 4
  for (int r = 0; r < 64; ++r) {
    int row = row0 + r;
    int seg = idxp[row];
    const int4 k4 = *(const int4*)(tab + (size_t)seg * KDIM + cg);
    f32x4 v;
    v[0] = fdec(k4.x); v[1] = fdec(k4.y); v[2] = fdec(k4.z); v[3] = fdec(k4.w);
#pragma unroll
    for (int j = 0; j < 4; ++j) v[j] = fmaxf(0.f, (v[j] - mu[j]) * sc[j] + bb[j]);
    __builtin_nontemporal_store(v, &out4[(size_t)row * 64 + lane]);
  }
}

extern "C" void kernel_launch(void* const* d_in, const int* in_sizes, int n_in,
                              void* d_out, int out_size, void* d_ws, size_t ws_size,
                              hipStream_t stream) {
  const float* x      = (const float*)d_in[0];
  const int*   batch  = (const int*)d_in[1];
  const int*   stroke = (const int*)d_in[2];
  const float* Wmax   = (const float*)d_in[3];
  const float* g_max  = (const float*)d_in[5];
  const float* be_max = (const float*)d_in[6];
  const float* Wsk    = (const float*)d_in[7];
  const float* g_sk   = (const float*)d_in[9];
  const float* be_sk  = (const float*)d_in[10];
  unsigned char* ws = (unsigned char*)d_ws;
  float* out = (float*)d_out;

  k_init <<<2048, 512, 0, stream>>>(Wmax, Wsk, ws);
  k_pass1<<<512, 512, 0, stream>>>(x, batch, stroke, ws);
  k_out  <<<2048, 256, 0, stream>>>(batch, stroke, g_max, be_max, g_sk, be_sk, ws, out);
}

// Round 20
// 224.860 us; speedup vs baseline: 1.0482x; 1.0482x over previous
//
#include <hip/hip_runtime.h>
#include <hip/hip_bf16.h>
#include <climits>
#include <cstdint>
#include <cfloat>

#define NROWS   524288
#define KDIM    128
#define NGRAPH  64
#define NSTROKE 8192
#define EPSF    1e-5f

typedef __bf16 bf16x8 __attribute__((ext_vector_type(8)));
typedef float  f32x4  __attribute__((ext_vector_type(4)));

// ws layout (bytes)
#define WT_OFF    0                         // ushort bf16 Wt[256][128] (col-major)
#define CSUM_OFF  65536                     // float[256]
#define CSQ_OFF   66560                     // float[256]
#define ST_OFF    67584                     // int [8192][128] stroke max (int-key)
#define GT_OFF    (ST_OFF + NSTROKE*KDIM*4) // int [64][128] graph max (int-key)

__device__ __forceinline__ unsigned short f2bf(float f) {
  unsigned int u = __float_as_uint(f);
  u += 0x7fffu + ((u >> 16) & 1u);   // RNE
  return (unsigned short)(u >> 16);
}
// order-preserving float<->int key (for atomicMax)
__device__ __forceinline__ int fkey(float f) {
  int b = __float_as_int(f);
  return b >= 0 ? b : (b ^ 0x7fffffff);
}
__device__ __forceinline__ float fdec(int k) {
  int b = k >= 0 ? k : (k ^ 0x7fffffff);
  return __int_as_float(b);
}

// ---------------- init: weights -> bf16 col-major; clear sums + max tables ----
__global__ void k_init(const float* __restrict__ Wmax, const float* __restrict__ Wsk,
                       unsigned char* __restrict__ ws) {
  unsigned short* wt = (unsigned short*)(ws + WT_OFF);
  float* csum = (float*)(ws + CSUM_OFF);
  float* csq  = (float*)(ws + CSQ_OFF);
  int* st = (int*)(ws + ST_OFF);
  int* gt = (int*)(ws + GT_OFF);
  int i = blockIdx.x * blockDim.x + threadIdx.x;
  const int total = NSTROKE * KDIM;   // 1048576
  for (; i < total; i += gridDim.x * blockDim.x) {
    st[i] = INT_MIN;
    if (i < NGRAPH * KDIM) gt[i] = INT_MIN;
    if (i < 256) { csum[i] = 0.f; csq[i] = 0.f; }
    if (i < 256 * KDIM) {
      int c = i / KDIM, k = i % KDIM;
      float w = (c < 128) ? Wsk[k * 128 + c] : Wmax[k * 128 + (c - 128)];
      wt[i] = f2bf(w);   // wt[c][k]
    }
  }
}

// ---------------- pass1: 8-wave SLIM pipelined GEMM + sums + seg max -----------
// FINAL (R18, proven 226.9us): 512 blocks x 16 tiles (2 resident blocks/CU
// from t=0), slim per-wave state (~120 VGPR) with __launch_bounds__(512,4)
// for 4 waves/SIMD, double-buffered LDS + issue-early register prefetch,
// boundary-mask prefetch (seg metadata computed one tile ahead), acc-direct
// segment max, hand-rolled f2bf staging (R15/R19 proved alternatives regress).
__global__ __launch_bounds__(512, 4) void k_pass1(const float* __restrict__ x,
                                                  const int* __restrict__ batch,
                                                  const int* __restrict__ stroke,
                                                  unsigned char* __restrict__ ws) {
  __shared__ __align__(16) unsigned short xs[2][64 * 128];  // 2 x 16 KB, swz
  const unsigned short* wt = (const unsigned short*)(ws + WT_OFF);
  float* csum = (float*)(ws + CSUM_OFF);
  float* csq  = (float*)(ws + CSQ_OFF);
  int* st = (int*)(ws + ST_OFF);
  int* gt = (int*)(ws + GT_OFF);

  const int tid  = threadIdx.x;
  const int lane = tid & 63;
  const int wv   = tid >> 6;   // wave 0..7
  const int lr   = lane & 15;
  const int lg   = lane >> 4;
  const int srow = tid >> 3;   // staging row (0..63)
  const int skg  = tid & 7;    // staging 16-float group

  const int colbase = wv * 32;            // combined col base
  const bool isS = (wv < 4);
  const int* __restrict__ segp = isS ? stroke : batch;
  int* __restrict__ tab = isS ? st : gt;
  const int tcol = colbase - (isS ? 0 : 128);

  // B fragments: lane holds Wt[col = colbase+n*16+lr][k = ks*32+lg*8 ..+7]
  bf16x8 bfrag[4][2];
#pragma unroll
  for (int ks = 0; ks < 4; ++ks)
#pragma unroll
    for (int n = 0; n < 2; ++n)
      bfrag[ks][n] = *(const bf16x8*)(wt + (colbase + n * 16 + lr) * KDIM + ks * 32 + lg * 8);

  float sumn[2] = {0.f, 0.f};
  float sqn[2]  = {0.f, 0.f};

  int   curseg = -1;
  float runmax[2] = {-FLT_MAX, -FLT_MAX};

#define FLUSH()                                                               \
  if (curseg >= 0) {                                                          \
    _Pragma("unroll")                                                         \
    for (int n = 0; n < 2; ++n) {                                             \
      float f = runmax[n];                                                    \
      f = fmaxf(f, __shfl_xor(f, 16));                                        \
      f = fmaxf(f, __shfl_xor(f, 32));                                        \
      if (lg == 0) atomicMax(&tab[curseg * KDIM + tcol + n * 16 + lr], fkey(f)); \
    }                                                                         \
  }

#define PF_LOAD(ROW0)                                                         \
  {                                                                           \
    const float* src = x + (size_t)((ROW0) + srow) * KDIM + skg * 16;         \
    pf[0] = *(const f32x4*)src;                                               \
    pf[1] = *(const f32x4*)(src + 4);                                         \
    pf[2] = *(const f32x4*)(src + 8);                                         \
    pf[3] = *(const f32x4*)(src + 12);                                        \
  }

#define PF_STORE(P)                                                           \
  {                                                                           \
    union { bf16x8 v; unsigned short u[8]; } pk;                              \
    pk.u[0] = f2bf(pf[0][0]); pk.u[1] = f2bf(pf[0][1]);                       \
    pk.u[2] = f2bf(pf[0][2]); pk.u[3] = f2bf(pf[0][3]);                       \
    pk.u[4] = f2bf(pf[1][0]); pk.u[5] = f2bf(pf[1][1]);                       \
    pk.u[6] = f2bf(pf[1][2]); pk.u[7] = f2bf(pf[1][3]);                       \
    *(bf16x8*)(xs[P] + srow * KDIM + (((skg * 2) ^ (srow & 7)) << 3)) = pk.v; \
    pk.u[0] = f2bf(pf[2][0]); pk.u[1] = f2bf(pf[2][1]);                       \
    pk.u[2] = f2bf(pf[2][2]); pk.u[3] = f2bf(pf[2][3]);                       \
    pk.u[4] = f2bf(pf[3][0]); pk.u[5] = f2bf(pf[3][1]);                       \
    pk.u[6] = f2bf(pf[3][2]); pk.u[7] = f2bf(pf[3][3]);                       \
    *(bf16x8*)(xs[P] + srow * KDIM + (((skg * 2 + 1) ^ (srow & 7)) << 3)) = pk.v; \
  }

// load seg ids for tile and derive (mask, seg0) immediately — off the
// epilogue critical path
#define SEG_PREP(ROW0, SV, MK, S0)                                            \
  {                                                                           \
    SV = segp[(ROW0) + lane];                                                 \
    int pv_ = __shfl_up(SV, 1);                                               \
    MK = __ballot(lane > 0 && pv_ != SV);                                     \
    S0 = __shfl(SV, 0);                                                       \
  }

  const int brow = blockIdx.x * 1024;   // 16 tiles x 64 rows
  f32x4 pf[4];
  int segv, seg0;
  unsigned long long mask;
  int segvN, seg0N;
  unsigned long long maskN;

  // ---- prologue: stage tile 0 ----
  PF_LOAD(brow);
  SEG_PREP(brow, segv, mask, seg0);
  PF_STORE(0);
  __syncthreads();

  int cur = 0;
  for (int ti = 0; ti < 16; ++ti) {
    // ---- issue next tile's global loads + seg prep (hidden under compute) ----
    if (ti < 15) {
      PF_LOAD(brow + (ti + 1) * 64);
      SEG_PREP(brow + (ti + 1) * 64, segvN, maskN, seg0N);
    }

    // ---- MFMA: 64 rows x 32 cols per wave, from xs[cur] ----
    f32x4 acc[4][2];
#pragma unroll
    for (int m = 0; m < 4; ++m)
#pragma unroll
      for (int n = 0; n < 2; ++n) { f32x4 z = {0.f, 0.f, 0.f, 0.f}; acc[m][n] = z; }

#pragma unroll
    for (int ks = 0; ks < 4; ++ks) {
      bf16x8 af[4];
#pragma unroll
      for (int m = 0; m < 4; ++m) {
        int r  = m * 16 + lr;
        int kg = ks * 4 + lg;
        af[m] = *(const bf16x8*)(xs[cur] + r * KDIM + ((kg ^ (r & 7)) << 3));
      }
#pragma unroll
      for (int m = 0; m < 4; ++m) {
        acc[m][0] = __builtin_amdgcn_mfma_f32_16x16x32_bf16(af[m], bfrag[ks][0], acc[m][0], 0, 0, 0);
        acc[m][1] = __builtin_amdgcn_mfma_f32_16x16x32_bf16(af[m], bfrag[ks][1], acc[m][1], 0, 0, 0);
      }
    }

    // ---- column sums/sumsq + tile col-max straight from accumulators ----
    float tm[2];
#pragma unroll
    for (int n = 0; n < 2; ++n) {
      float s = 0.f, q = 0.f, t = -FLT_MAX;
#pragma unroll
      for (int m = 0; m < 4; ++m)
#pragma unroll
        for (int rg = 0; rg < 4; ++rg) {
          float v = acc[m][n][rg];
          s += v; q = fmaf(v, v, q); t = fmaxf(t, v);
        }
      sumn[n] += s; sqn[n] += q; tm[n] = t;
    }

    // ---- acc-direct segment max; (mask, seg0) precomputed last iteration ----
    {
      if (mask == 0ull) {
        if (seg0 == curseg) {
#pragma unroll
          for (int n = 0; n < 2; ++n) runmax[n] = fmaxf(runmax[n], tm[n]);
        } else {
          FLUSH();
          curseg = seg0;
#pragma unroll
          for (int n = 0; n < 2; ++n) runmax[n] = tm[n];
        }
      } else {
        unsigned long long rem = mask;
        int a = 0;
        while (true) {
          int b = rem ? (int)__builtin_ctzll(rem) : 64;
          int segr = (a == 0) ? seg0 : __shfl(segv, a);
          float rm[2] = {-FLT_MAX, -FLT_MAX};
#pragma unroll
          for (int m = 0; m < 4; ++m)
#pragma unroll
            for (int rg = 0; rg < 4; ++rg) {
              int pos = m * 16 + lg * 4 + rg;
              bool in = (pos >= a) && (pos < b);
#pragma unroll
              for (int n = 0; n < 2; ++n)
                rm[n] = in ? fmaxf(rm[n], acc[m][n][rg]) : rm[n];
            }
          if (a == 0 && segr == curseg) {
#pragma unroll
            for (int n = 0; n < 2; ++n) runmax[n] = fmaxf(runmax[n], rm[n]);
          } else {
            FLUSH();
            curseg = segr;
#pragma unroll
            for (int n = 0; n < 2; ++n) runmax[n] = rm[n];
          }
          if (b >= 64) break;
          rem &= rem - 1; a = b;
        }
      }
    }

    // ---- write next tile into the other LDS buffer; one barrier per tile ----
    if (ti < 15) {
      PF_STORE(cur ^ 1);
      segv = segvN; mask = maskN; seg0 = seg0N;
    }
    __syncthreads();
    cur ^= 1;
  }

  FLUSH();   // final carried run

  // ---- finalize sums: reduce over the 4 k-group lanes, atomics at lg==0 ----
#pragma unroll
  for (int n = 0; n < 2; ++n) {
    float s = sumn[n], q = sqn[n];
    s += __shfl_xor(s, 16); s += __shfl_xor(s, 32);
    q += __shfl_xor(q, 16); q += __shfl_xor(q, 32);
    if (lg == 0) {
      atomicAdd(&csum[colbase + n * 16 + lr], s);
      atomicAdd(&csq [colbase + n * 16 + lr], q);
    }
  }
#undef FLUSH
#undef PF_LOAD
#undef PF_STORE
#undef SEG_PREP
}

// ---------------- out: gather + BN(affine)+ReLU on the fly + stream write ------
// (R2-exact)
__global__ __launch_bounds__(256) void k_out(const int* __restrict__ batch,
                                             const int* __restrict__ stroke,
                                             const float* __restrict__ g_max,
                                             const float* __restrict__ be_max,
                                             const float* __restrict__ g_sk,
                                             const float* __restrict__ be_sk,
                                             const unsigned char* __restrict__ ws,
                                             float* __restrict__ out) {
  const float* csum = (const float*)(ws + CSUM_OFF);
  const float* csq  = (const float*)(ws + CSQ_OFF);
  const int* st = (const int*)(ws + ST_OFF);
  const int* gt = (const int*)(ws + GT_OFF);

  const int lane = threadIdx.x & 63;
  const int wvid = blockIdx.x * 4 + (threadIdx.x >> 6);
  const int row0 = wvid * 64;
  const bool isS = lane < 32;
  const int  cg  = (isS ? lane : lane - 32) * 4;
  const int* tab  = isS ? st : gt;
  const int* idxp = isS ? stroke : batch;
  const float* gv = isS ? g_sk : g_max;
  const float* bv = isS ? be_sk : be_max;

  const float invN = 1.0f / (float)NROWS;
  f32x4 mu, sc, bb;
#pragma unroll
  for (int j = 0; j < 4; ++j) {
    int cc = (isS ? 0 : 128) + cg + j;
    float m  = csum[cc] * invN;
    float vr = csq[cc] * invN - m * m;
    mu[j] = m;
    sc[j] = gv[cg + j] * rsqrtf(vr + EPSF);
    bb[j] = bv[cg + j];
  }

  f32x4* out4 = (f32x4*)out;
#pragma unroll 4
  for (int r = 0; r < 64; ++r) {
    int row = row0 + r;
    int seg = idxp[row];
    const int4 k4 = *(const int4*)(tab + (size_t)seg * KDIM + cg);
    f32x4 v;
    v[0] = fdec(k4.x); v[1] = fdec(k4.y); v[2] = fdec(k4.z); v[3] = fdec(k4.w);
#pragma unroll
    for (int j = 0; j < 4; ++j) v[j] = fmaxf(0.f, (v[j] - mu[j]) * sc[j] + bb[j]);
    __builtin_nontemporal_store(v, &out4[(size_t)row * 64 + lane]);
  }
}

extern "C" void kernel_launch(void* const* d_in, const int* in_sizes, int n_in,
                              void* d_out, int out_size, void* d_ws, size_t ws_size,
                              hipStream_t stream) {
  const float* x      = (const float*)d_in[0];
  const int*   batch  = (const int*)d_in[1];
  const int*   stroke = (const int*)d_in[2];
  const float* Wmax   = (const float*)d_in[3];
  const float* g_max  = (const float*)d_in[5];
  const float* be_max = (const float*)d_in[6];
  const float* Wsk    = (const float*)d_in[7];
  const float* g_sk   = (const float*)d_in[9];
  const float* be_sk  = (const float*)d_in[10];
  unsigned char* ws = (unsigned char*)d_ws;
  float* out = (float*)d_out;

  k_init <<<2048, 512, 0, stream>>>(Wmax, Wsk, ws);
  k_pass1<<<512, 512, 0, stream>>>(x, batch, stroke, ws);
  k_out  <<<2048, 256, 0, stream>>>(batch, stroke, g_max, be_max, g_sk, be_sk, ws, out);
}